// Round 3
// baseline (910.644 us; speedup 1.0000x reference)
//
#include <hip/hip_runtime.h>
#include <hip/hip_bf16.h>
#include <stdint.h>

// Problem: score [2,16,2048,2048] fp32, value [2,16,2048,128] fp32
// out[bh] = (fq(score) . fq(value)) * qs*ks  -- integer-valued matmul, exact in bf16 MFMA
#define S_DIM 2048
#define D_DIM 128
#define BH_N  32
#define BM    64
#define BK    64
#define ASTR  72   // padded k-stride (bf16) for the vt transpose staging tile

typedef float  f32x4  __attribute__((ext_vector_type(4)));
typedef unsigned int u32x4 __attribute__((ext_vector_type(4)));
typedef short  bf16x8 __attribute__((ext_vector_type(8)));

// fake_quant one float -> integer-valued bf16 (exact: |q| <= 129 < 256)
__device__ __forceinline__ unsigned short quant1(float v, float inv) {
    float q = rintf(v * inv);              // v_rndne_f32 == jnp.round (RNE)
    q = fminf(fmaxf(q, -129.0f), 127.0f);  // faithful MIN_INT = -129
    return (unsigned short)(__float_as_uint(q) >> 16);  // exact bf16 truncation
}

__device__ __forceinline__ bf16x8 quant8(f32x4 a, f32x4 b, float inv) {
    bf16x8 r;
    r[0] = (short)quant1(a.x, inv); r[1] = (short)quant1(a.y, inv);
    r[2] = (short)quant1(a.z, inv); r[3] = (short)quant1(a.w, inv);
    r[4] = (short)quant1(b.x, inv); r[5] = (short)quant1(b.y, inv);
    r[6] = (short)quant1(b.z, inv); r[7] = (short)quant1(b.w, inv);
    return r;
}

// ---------------------------------------------------------------------------
// Kernel 1: quantize value and transpose to vt[bh][d][k] (bf16, k-contiguous)
// ---------------------------------------------------------------------------
__global__ __launch_bounds__(256) void vt_quant_kernel(
        const float* __restrict__ value,
        const float* __restrict__ ks_p,
        unsigned short* __restrict__ vt) {
    __shared__ unsigned short T[D_DIM * ASTR];  // [d][k] padded

    const int bid = blockIdx.x;
    const int bh  = bid >> 5;
    const int k0  = (bid & 31) * BK;
    const float inv = 1.0f / ks_p[0];
    const int tid = threadIdx.x;

    const float* src = value + ((size_t)bh * S_DIM + k0) * D_DIM;

#pragma unroll
    for (int i = 0; i < 8; ++i) {
        int f  = tid + 256 * i;         // 0..2047 float4s of the 64x128 tile
        int k  = f >> 5;                // 0..63
        int c4 = (f & 31) * 4;          // d base 0..124
        f32x4 v = *(const f32x4*)(src + (size_t)k * D_DIM + c4);
        T[(c4 + 0) * ASTR + k] = quant1(v.x, inv);
        T[(c4 + 1) * ASTR + k] = quant1(v.y, inv);
        T[(c4 + 2) * ASTR + k] = quant1(v.z, inv);
        T[(c4 + 3) * ASTR + k] = quant1(v.w, inv);
    }
    __syncthreads();

    unsigned short* dst = vt + (size_t)bh * D_DIM * S_DIM + k0;
#pragma unroll
    for (int i = 0; i < 4; ++i) {
        int c = tid + 256 * i;          // 0..1023 16B-chunks (128 d x 8 chunks)
        int n = c >> 3;                 // d row 0..127
        int q = (c & 7) * 8;            // k offset within tile
        u32x4 x = *(const u32x4*)(&T[n * ASTR + q]);
        *(u32x4*)(dst + (size_t)n * S_DIM + q) = x;
    }
}

// ---------------------------------------------------------------------------
// Kernel 2: BARRIER-FREE fused quantize(score) + bf16 MFMA GEMM.
// No LDS, no __syncthreads in the K-loop: every lane loads its own MFMA
// fragments directly from global (A: 32B contiguous fp32 -> quant in reg;
// B: 16B contiguous bf16 from cache-resident vt). Each wave stalls only on
// its own vmcnt -> latency hidden by 12-16 independent waves/CU.
// Block = 256 thr (4 waves). Wave w owns m-rows [w*16, w*16+16), all n=128.
// 1024 blocks, XCD-swizzled so each XCD's L2 holds only 4 vt slabs (2 MB).
// ---------------------------------------------------------------------------
__global__ __launch_bounds__(256) void bmm_kernel(
        const float* __restrict__ score,
        const unsigned short* __restrict__ vt,
        const float* __restrict__ qs_p,
        const float* __restrict__ ks_p,
        float* __restrict__ out) {
    const int bid = blockIdx.x;
    // XCD-aware swizzle: xcd = bid&7 (dispatch heuristic); blocks resident on
    // one XCD cover bh in {4*xcd .. 4*xcd+3} -> 4 vt slabs = 2 MB <= 4 MB L2.
    const int bh  = (bid & 7) * 4 + (bid >> 8);
    const int m0  = ((bid >> 3) & 31) * BM;

    const float inv_qs = 1.0f / qs_p[0];
    const float fin = qs_p[0] * ks_p[0];

    const int tid  = threadIdx.x;
    const int lane = tid & 63;
    const int wave = tid >> 6;
    const int m16  = lane & 15;
    const int quad = lane >> 4;

    // this lane's A row (fp32) and B base row (bf16, k-contiguous)
    const float* Ar = score + (size_t)bh * S_DIM * S_DIM
                            + (size_t)(m0 + wave * 16 + m16) * S_DIM;
    const unsigned short* Br = vt + (size_t)bh * D_DIM * S_DIM
                                  + (size_t)m16 * S_DIM;

    f32x4 acc[8] = {};

    for (int kb = 0; kb < S_DIM; kb += BK) {
#pragma unroll
        for (int kk = 0; kk < BK; kk += 32) {
            const int ko = kb + kk + quad * 8;
            f32x4 a0 = __builtin_nontemporal_load((const f32x4*)(Ar + ko));
            f32x4 a1 = __builtin_nontemporal_load((const f32x4*)(Ar + ko + 4));
            bf16x8 af = quant8(a0, a1, inv_qs);
#pragma unroll
            for (int j = 0; j < 8; ++j) {
                bf16x8 bf = *(const bf16x8*)(Br + (size_t)(j * 16) * S_DIM + ko);
                acc[j] = __builtin_amdgcn_mfma_f32_16x16x32_bf16(af, bf, acc[j], 0, 0, 0);
            }
        }
    }

    // epilogue: C/D layout col(n) = j*16 + m16, row(m) = quad*4 + r
    float* O = out + (size_t)bh * S_DIM * D_DIM
                   + (size_t)(m0 + wave * 16 + quad * 4) * D_DIM + m16;
#pragma unroll
    for (int j = 0; j < 8; ++j)
#pragma unroll
        for (int r = 0; r < 4; ++r)
            O[(size_t)r * D_DIM + j * 16] = acc[j][r] * fin;
}

extern "C" void kernel_launch(void* const* d_in, const int* in_sizes, int n_in,
                              void* d_out, int out_size, void* d_ws, size_t ws_size,
                              hipStream_t stream) {
    const float* score = (const float*)d_in[0];
    const float* value = (const float*)d_in[1];
    const float* qs    = (const float*)d_in[2];
    const float* ks    = (const float*)d_in[3];
    float* out = (float*)d_out;
    unsigned short* vt = (unsigned short*)d_ws;  // 32*128*2048*2 = 16 MiB

    vt_quant_kernel<<<BH_N * (S_DIM / BK), 256, 0, stream>>>(value, ks, vt);
    bmm_kernel<<<BH_N * (S_DIM / BM), 256, 0, stream>>>(score, vt, qs, ks, out);
}

// Round 4
// 757.688 us; speedup vs baseline: 1.2019x; 1.2019x over previous
//
#include <hip/hip_runtime.h>
#include <hip/hip_bf16.h>
#include <stdint.h>

// Problem: score [2,16,2048,2048] fp32, value [2,16,2048,128] fp32
// out[bh] = (fq(score) . fq(value)) * qs*ks  -- integer-valued matmul, exact in bf16 MFMA
#define S_DIM 2048
#define D_DIM 128
#define BH_N  32
#define ASTR  72    // shorts; kernel-1 transpose tile stride
#define AWSTR 136   // shorts; wave-private A tile row stride (128 k + 8 pad)

typedef float  f32x4  __attribute__((ext_vector_type(4)));
typedef unsigned int u32x2 __attribute__((ext_vector_type(2)));
typedef unsigned int u32x4 __attribute__((ext_vector_type(4)));
typedef short  bf16x8 __attribute__((ext_vector_type(8)));

// fake_quant one float -> integer-valued bf16 (exact: |q| <= 129 < 256)
// returns the bf16 pattern in the LOW 16 bits
__device__ __forceinline__ unsigned int quant1(float v, float inv) {
    float q = rintf(v * inv);              // v_rndne_f32 == jnp.round (RNE)
    q = fminf(fmaxf(q, -129.0f), 127.0f);  // faithful MIN_INT = -129
    return __float_as_uint(q) >> 16;       // exact bf16 truncation
}

// ---------------------------------------------------------------------------
// Kernel 1: quantize value and store in MFMA B-FRAGMENT ORDER:
//   vt[bh][ks][j][lane][e]  (ks=k/32, j=n/16, lane=(n&15)|(quad<<4), e=0..7)
// so that bmm's B-fragment load is base + lane*16B: perfectly coalesced.
// Layout matches the b-frag mapping verified in R2/R3 (absmax==0):
//   lane l holds Vq[n = j*16 + (l&15)][k = ks*32 + (l>>4)*8 + e]
// ---------------------------------------------------------------------------
__global__ __launch_bounds__(256) void vt_quant_kernel(
        const float* __restrict__ value,
        const float* __restrict__ ks_p,
        unsigned short* __restrict__ vt) {
    __shared__ unsigned short T[D_DIM * ASTR];  // [d][k] padded

    const int bid = blockIdx.x;
    const int bh  = bid >> 5;
    const int k0  = (bid & 31) * 64;            // 64-wide k tile
    const float inv = 1.0f / ks_p[0];
    const int tid = threadIdx.x;

    const float* src = value + ((size_t)bh * S_DIM + k0) * D_DIM;

#pragma unroll
    for (int i = 0; i < 8; ++i) {
        int f  = tid + 256 * i;         // 0..2047 float4s of the 64x128 tile
        int k  = f >> 5;                // 0..63
        int c4 = (f & 31) * 4;          // d base 0..124
        f32x4 v = *(const f32x4*)(src + (size_t)k * D_DIM + c4);
        T[(c4 + 0) * ASTR + k] = (unsigned short)quant1(v.x, inv);
        T[(c4 + 1) * ASTR + k] = (unsigned short)quant1(v.y, inv);
        T[(c4 + 2) * ASTR + k] = (unsigned short)quant1(v.z, inv);
        T[(c4 + 3) * ASTR + k] = (unsigned short)quant1(v.w, inv);
    }
    __syncthreads();

    unsigned short* dstb = vt + (size_t)bh * D_DIM * S_DIM;  // 512 KB slab
    const int ksg0 = k0 >> 5;                                 // global ks base
#pragma unroll
    for (int i = 0; i < 4; ++i) {
        int g   = i * 256 + tid;        // 0..1023 fragment chunks
        int l   = g & 63;
        int j   = (g >> 6) & 7;
        int ksl = g >> 9;               // 0..1
        int d   = j * 16 + (l & 15);
        int kl  = ksl * 32 + (l >> 4) * 8;
        u32x4 x = *(const u32x4*)(&T[d * ASTR + kl]);
        size_t off = ((size_t)((ksg0 + ksl) * 8 + j) * 64 + l) * 8;
        *(u32x4*)(dstb + off) = x;      // consecutive l -> coalesced 4 KB
    }
}

// ---------------------------------------------------------------------------
// Kernel 2: ZERO-BARRIER fused quantize(score) + bf16 MFMA GEMM.
// Each wave independently owns one (bh, 16-row m-tile), all n=128.
//  - A: coalesced 16x128 fp32 macro-loads -> quant -> WAVE-PRIVATE LDS
//    (same-wave write/read: only lgkmcnt, no __syncthreads ever)
//  - B: direct-from-global fragment loads from frag-ordered vt
//    (base + lane*16B: 1 coalesced KB/instr, L2-resident slab)
//  - manual A prefetch kept in flight across the MFMA phase; nothing drains it
// 1024 blocks x 4 waves; XCD swizzle keeps 4 vt slabs (2 MB) per XCD L2.
// ---------------------------------------------------------------------------
__global__ __launch_bounds__(256, 3) void bmm_kernel(
        const float* __restrict__ score,
        const unsigned short* __restrict__ vt,
        const float* __restrict__ qs_p,
        const float* __restrict__ ks_p,
        float* __restrict__ out) {
    __shared__ unsigned short Aw[4][16 * AWSTR];  // 4 x 4352 B, wave-private

    const int bid  = blockIdx.x;
    const int bh   = (bid & 7) * 4 + (bid >> 8);  // XCD-aware: 4 bh per XCD
    const int tid  = threadIdx.x;
    const int lane = tid & 63;
    const int wave = tid >> 6;
    const int M0   = (((bid >> 3) & 31) * 4 + wave) * 16;  // wave's 16 rows
    const int m16  = lane & 15;
    const int quad = lane >> 4;
    const int arow = lane >> 5;          // 0/1: row within a 2-row load pair
    const int acol = (lane & 31) * 4;    // 0..124

    const float inv_qs = 1.0f / qs_p[0];
    const float fin = qs_p[0] * ks_p[0];

    const float* A = score + (size_t)bh * S_DIM * S_DIM + (size_t)M0 * S_DIM;
    const unsigned short* Bf = vt + (size_t)bh * D_DIM * S_DIM + (size_t)lane * 8;

    unsigned short* aw = Aw[wave];

    f32x4 acc[8] = {};
    f32x4 av[2][8];

    // preload macro-tile t=0 (16 rows x 128 k, 2-segment coalesced per instr)
#pragma unroll
    for (int i = 0; i < 8; ++i)
        av[0][i] = __builtin_nontemporal_load(
            (const f32x4*)(A + (size_t)(2 * i + arow) * S_DIM + acol));

#pragma unroll 2
    for (int t = 0; t < 16; ++t) {
        const int p = t & 1;
        // quantize current macro-tile into wave-private LDS (no barrier)
#pragma unroll
        for (int i = 0; i < 8; ++i) {
            u32x2 wv;
            wv.x = quant1(av[p][i].x, inv_qs) | (quant1(av[p][i].y, inv_qs) << 16);
            wv.y = quant1(av[p][i].z, inv_qs) | (quant1(av[p][i].w, inv_qs) << 16);
            *(u32x2*)(&aw[(2 * i + arow) * AWSTR + acol]) = wv;
        }
        // prefetch next macro-tile; stays in flight through the MFMA phase
        if (t < 15) {
            const int kn = (t + 1) * 128;
#pragma unroll
            for (int i = 0; i < 8; ++i)
                av[p ^ 1][i] = __builtin_nontemporal_load(
                    (const f32x4*)(A + (size_t)(2 * i + arow) * S_DIM + kn + acol));
        }
        // 4 K-substeps of 32: af from private LDS, B straight from global
#pragma unroll
        for (int s = 0; s < 4; ++s) {
            bf16x8 af = *(const bf16x8*)(&aw[m16 * AWSTR + s * 32 + quad * 8]);
            const unsigned short* bp = Bf + (size_t)(t * 4 + s) * 4096;
#pragma unroll
            for (int j = 0; j < 8; ++j) {
                bf16x8 bv = *(const bf16x8*)(bp + j * 512);
                acc[j] = __builtin_amdgcn_mfma_f32_16x16x32_bf16(af, bv, acc[j], 0, 0, 0);
            }
        }
    }

    // epilogue: C/D layout col(n) = j*16 + m16, row(m) = quad*4 + r  (verified R3)
    float* O = out + (size_t)bh * S_DIM * D_DIM
                   + (size_t)(M0 + quad * 4) * D_DIM + m16;
#pragma unroll
    for (int j = 0; j < 8; ++j)
#pragma unroll
        for (int r = 0; r < 4; ++r)
            O[(size_t)r * D_DIM + j * 16] = acc[j][r] * fin;
}

extern "C" void kernel_launch(void* const* d_in, const int* in_sizes, int n_in,
                              void* d_out, int out_size, void* d_ws, size_t ws_size,
                              hipStream_t stream) {
    const float* score = (const float*)d_in[0];
    const float* value = (const float*)d_in[1];
    const float* qs    = (const float*)d_in[2];
    const float* ks    = (const float*)d_in[3];
    float* out = (float*)d_out;
    unsigned short* vt = (unsigned short*)d_ws;  // 32*128*2048*2 = 16 MiB

    vt_quant_kernel<<<BH_N * (S_DIM / 64), 256, 0, stream>>>(value, ks, vt);
    bmm_kernel<<<1024, 256, 0, stream>>>(score, vt, qs, ks, out);
}